// Round 1
// baseline (221.234 us; speedup 1.0000x reference)
//
#include <hip/hip_runtime.h>

#define NI 128
#define NA 285
#define ND 183
#define NT 384
#define LDSW 131   // 128 data + 1 low border + 2 high border (zero padding)

constexpr float PI_F  = 3.14159265358979323846f;
constexpr float RHO_F = 28.284271247461902f;   // 20*sqrt(2)
constexpr float DX_F  = 40.0f / 128.0f;        // 0.3125
constexpr float DT_F  = 2.0f * RHO_F / NT;

// One block handles one batch image and TWO angles (384 threads = 2 x 192,
// dets 0..182 active per angle). Image staged in LDS with a zero border so
// the bilinear inner loop needs no bounds checks at all: coords clamped to
// [-1, 128] always read valid LDS, and any OOB neighbor reads a zero cell,
// matching map_coordinates(mode='constant', cval=0).
__global__ __launch_bounds__(384) void radon_fwd(const float* __restrict__ x,
                                                 float* __restrict__ out) {
    __shared__ float img[LDSW * LDSW];   // 131*131*4 = 68,644 B
    const int tid = threadIdx.x;
    const int b = blockIdx.y;

    // Phase 1: zero the whole padded tile.
    for (int i = tid; i < LDSW * LDSW; i += 384) img[i] = 0.0f;
    __syncthreads();

    // Phase 2: load interior rows (coalesced float4 global reads).
    const float4* src = (const float4*)(x + b * NI * NI);
    for (int i = tid; i < NI * NI / 4; i += 384) {
        float4 v = src[i];
        int e = i * 4;
        int row = e >> 7;      // e / 128
        int col = e & 127;     // e % 128  (float4 never crosses a row)
        float* dst = &img[(row + 1) * LDSW + (col + 1)];
        dst[0] = v.x; dst[1] = v.y; dst[2] = v.z; dst[3] = v.w;
    }
    __syncthreads();

    const int asub = tid / 192;            // which of the 2 angles
    const int det  = tid - asub * 192;     // 0..191, valid < 183
    const int a    = blockIdx.x * 2 + asub;
    if (a >= NA || det >= ND) return;      // after all barriers — safe

    const float ang = ((float)a + 0.5f) * (PI_F / (float)NA);
    float sn, cs;
    sincosf(ang, &sn, &cs);
    const float s      = -RHO_F + ((float)det + 0.5f) * (2.0f * RHO_F / (float)ND);
    const float t0     = -RHO_F + 0.5f * DT_F;
    const float inv_dx = 1.0f / DX_F;
    // i0(k) = c0 + k*st0 ; i1(k) = c1 + k*st1
    const float c0  = (-s * sn + t0 * cs + 20.0f) * inv_dx - 0.5f;
    const float c1  = ( s * cs + t0 * sn + 20.0f) * inv_dx - 0.5f;
    const float st0 = DT_F * cs * inv_dx;
    const float st1 = DT_F * sn * inv_dx;

    float acc = 0.0f;
    float kf  = 0.0f;
    #pragma unroll 4
    for (int k = 0; k < NT; ++k) {
        float i0 = fmaf(kf, st0, c0);
        float i1 = fmaf(kf, st1, c1);
        kf += 1.0f;
        // Clamp to [-1, 128]: outside that, all 4 neighbors are zero cells.
        i0 = fminf(fmaxf(i0, -1.0f), 128.0f);
        i1 = fminf(fmaxf(i1, -1.0f), 128.0f);
        float f0 = floorf(i0);
        float f1 = floorf(i1);
        float a0 = i0 - f0;
        float a1 = i1 - f1;
        int r = (int)f0;           // -1..128
        int c = (int)f1;           // -1..128
        const float* p = &img[(r + 1) * LDSW + (c + 1)];   // rows/cols 0..130
        float v00 = p[0];
        float v01 = p[1];
        float v10 = p[LDSW];
        float v11 = p[LDSW + 1];
        float top = fmaf(a1, v01 - v00, v00);
        float bot = fmaf(a1, v11 - v10, v10);
        acc += fmaf(a0, bot - top, top);
    }

    out[(b * NA + a) * ND + det] = acc * (DT_F / 12.0f);
}

extern "C" void kernel_launch(void* const* d_in, const int* in_sizes, int n_in,
                              void* d_out, int out_size, void* d_ws, size_t ws_size,
                              hipStream_t stream) {
    const float* x = (const float*)d_in[0];
    float* out = (float*)d_out;
    const int B = in_sizes[0] / (NI * NI);   // 8
    dim3 grid((NA + 1) / 2, B);
    radon_fwd<<<grid, 384, 0, stream>>>(x, out);
}

// Round 2
// 138.480 us; speedup vs baseline: 1.5976x; 1.5976x over previous
//
#include <hip/hip_runtime.h>

#define NI 128
#define NA 285
#define ND 183
#define NT 384
#define RAYS (NA * ND)      // 52155
#define LDSW 133            // row stride: 128 data + 2 low ring + 3 spare/high
#define LDSH 132            // rows 0..131 (data rows at +2)

constexpr float PI_F  = 3.14159265358979323846f;
constexpr float RHO_F = 28.284271247461902f;   // 20*sqrt(2)
constexpr float DX_F  = 40.0f / 128.0f;        // 0.3125
constexpr float DT_F  = 2.0f * RHO_F / NT;

// One block = one batch image + 1024 rays (flat over angle*det).
// Image staged in LDS with a 2-cell zero ring; rays clipped to the bilinear
// support square |p| <= 20 + DX/2 so the inner loop has no bounds logic and
// ~40% fewer iterations (samples outside the image contribute exactly 0).
__global__ __launch_bounds__(1024, 8) void radon_fwd(const float* __restrict__ x,
                                                     float* __restrict__ out) {
    __shared__ float img[LDSH * LDSW];   // 132*133*4 = 70,224 B -> 2 blocks/CU
    const int tid = threadIdx.x;
    const int b = blockIdx.y;

    for (int i = tid; i < LDSH * LDSW; i += 1024) img[i] = 0.0f;
    __syncthreads();

    const float4* src = (const float4*)(x + b * NI * NI);
    for (int i = tid; i < NI * NI / 4; i += 1024) {
        float4 v = src[i];
        int e = i * 4;
        int row = e >> 7;
        int col = e & 127;
        float* dst = &img[(row + 2) * LDSW + (col + 2)];
        dst[0] = v.x; dst[1] = v.y; dst[2] = v.z; dst[3] = v.w;
    }
    __syncthreads();

    const int ray = blockIdx.x * 1024 + tid;
    if (ray >= RAYS) return;               // after all barriers — safe
    const int a   = ray / ND;              // const-div -> magic multiply
    const int det = ray - a * ND;

    const float ang = ((float)a + 0.5f) * (PI_F / (float)NA);
    float sn, cs;
    sincosf(ang, &sn, &cs);                // sn > 0 for all angles
    const float s   = -RHO_F + ((float)det + 0.5f) * (2.0f * RHO_F / (float)ND);
    const float t0v = -RHO_F + 0.5f * DT_F;
    const float inv_dx = 1.0f / DX_F;

    // p(t) = (e0 + t*cs, e1 + t*sn)
    const float e0 = -s * sn;
    const float e1 =  s * cs;
    // index i0(k) = c0 + k*st0, i1(k) = c1 + k*st1
    const float c0  = (e0 + t0v * cs + 20.0f) * inv_dx - 0.5f;
    const float c1  = (e1 + t0v * sn + 20.0f) * inv_dx - 0.5f;
    const float st0 = DT_F * cs * inv_dx;
    const float st1 = DT_F * sn * inv_dx;

    // Clip t to |p| <= LIM (bilinear support + margin; ring absorbs fp slop).
    const float LIM = 20.157f;
    const float inv_cs = 1.0f / cs;        // never exactly 0 in fp32
    const float inv_sn = 1.0f / sn;
    float ta = (-LIM - e0) * inv_cs, tb = (LIM - e0) * inv_cs;
    float tc = (-LIM - e1) * inv_sn, td = (LIM - e1) * inv_sn;
    float tlo = fmaxf(fminf(ta, tb), fminf(tc, td));
    float thi = fminf(fmaxf(ta, tb), fmaxf(tc, td));

    const float inv_dt = 1.0f / DT_F;
    float fk0 = ceilf((tlo - t0v) * inv_dt);
    float fk1 = floorf((thi - t0v) * inv_dt);
    fk0 = fmaxf(fk0, 0.0f);
    fk1 = fminf(fk1, (float)(NT - 1));
    // v_cvt_i32_f32 saturates: degenerate rays (fk0 huge / fk1 -huge or
    // fk0 > fk1) make the loop trip zero times.
    int kmin = (int)fk0;
    int kmax = (int)fk1;

    float acc = 0.0f;
    #pragma unroll 4
    for (int k = kmin; k <= kmax; ++k) {
        float fk = (float)k;
        float i0 = fmaf(fk, st0, c0);      // in [-1.003, 128.003] by clip
        float i1 = fmaf(fk, st1, c1);
        float f0 = floorf(i0);
        float f1 = floorf(i1);
        float a0 = i0 - f0;
        float a1 = i1 - f1;
        int r = (int)f0;                   // -2..128
        int c = (int)f1;
        const float* p = &img[(r + 2) * LDSW + (c + 2)];
        float v00 = p[0];
        float v01 = p[1];
        float v10 = p[LDSW];
        float v11 = p[LDSW + 1];
        float top = fmaf(a1, v01 - v00, v00);
        float bot = fmaf(a1, v11 - v10, v10);
        acc += fmaf(a0, bot - top, top);
    }

    out[b * RAYS + ray] = acc * (DT_F / 12.0f);
}

extern "C" void kernel_launch(void* const* d_in, const int* in_sizes, int n_in,
                              void* d_out, int out_size, void* d_ws, size_t ws_size,
                              hipStream_t stream) {
    const float* x = (const float*)d_in[0];
    float* out = (float*)d_out;
    const int B = in_sizes[0] / (NI * NI);   // 8
    dim3 grid((RAYS + 1023) / 1024, B);
    radon_fwd<<<grid, 1024, 0, stream>>>(x, out);
}

// Round 4
// 137.734 us; speedup vs baseline: 1.6062x; 1.0054x over previous
//
#include <hip/hip_runtime.h>
#include <stdint.h>

#define NI 128
#define NA 285
#define ND 183
#define NT 384
#define RAYS (NA * ND)        // 52155
#define PITCH 133             // dwords per packed row (odd -> bank-friendly)
#define PROWS 132
#define PLDS (PROWS * PITCH)  // 17556 dwords = 70,224 B -> 2 blocks/CU
#define RPB 815               // rays per block (64 blocks/image x 815 >= 52155)
#define TPB 832               // 13 waves

typedef __fp16 half2v __attribute__((ext_vector_type(2)));

constexpr float PI_F  = 3.14159265358979323846f;
constexpr float RHO_F = 28.284271247461902f;   // 20*sqrt(2)
constexpr float DX_F  = 0.3125f;
constexpr float DT_F  = 2.0f * RHO_F / NT;

// Packed-pair LDS Radon: P[pr][pc] = half2(pad[pr][pc], pad[pr+1][pc]) where
// pad is the image with a 2-cell zero ring (padded coords = index + 2).
// One ds_read2_b32 fetches all 4 bilinear neighbors; v_dot2_f32_f16 does the
// vertical lerp. Wave-uniform k-loop: out-of-chord samples clamp into the
// zero ring and contribute exactly 0 (no exec-mask bookkeeping).
__global__ __launch_bounds__(TPB) void radon_fwd(const float* __restrict__ x,
                                                 float* __restrict__ out) {
    __shared__ __align__(16) unsigned int P[PLDS];
    const int tid   = threadIdx.x;
    const int img   = blockIdx.x >> 6;
    const int chunk = blockIdx.x & 63;

    // Zero-fill (covers the ring; interior overwritten below).
    uint4* P4 = (uint4*)P;
    for (int i = tid; i < PLDS / 4; i += TPB) P4[i] = make_uint4(0, 0, 0, 0);
    __syncthreads();

    // Interior pack: rows pr in [1,129] have a nonzero half; 32 float4 groups
    // per row. low half = pad[pr] = x[pr-2], high half = pad[pr+1] = x[pr-1].
    const float4* src = (const float4*)(x + img * NI * NI);
    for (int i = tid; i < 129 * 32; i += TPB) {
        int pr  = 1 + (i >> 5);
        int g   = i & 31;
        int rlo = pr - 2;              // -1..127
        int rhi = pr - 1;              //  0..128
        float4 vlo = (rlo >= 0)  ? src[rlo * 32 + g] : make_float4(0, 0, 0, 0);
        float4 vhi = (rhi <= 127) ? src[rhi * 32 + g] : make_float4(0, 0, 0, 0);
        int base = pr * PITCH + 2 + g * 4;
        P[base + 0] = __builtin_bit_cast(unsigned int, __builtin_amdgcn_cvt_pkrtz(vlo.x, vhi.x));
        P[base + 1] = __builtin_bit_cast(unsigned int, __builtin_amdgcn_cvt_pkrtz(vlo.y, vhi.y));
        P[base + 2] = __builtin_bit_cast(unsigned int, __builtin_amdgcn_cvt_pkrtz(vlo.z, vhi.z));
        P[base + 3] = __builtin_bit_cast(unsigned int, __builtin_amdgcn_cvt_pkrtz(vlo.w, vhi.w));
    }
    __syncthreads();

    const int  lray  = chunk * RPB + tid;                 // ray within image
    const bool valid = (tid < RPB) && (lray < RAYS);

    const int a   = lray / ND;          // magic-multiply (const divisor)
    const int det = lray - a * ND;

    const float ang = ((float)a + 0.5f) * (PI_F / (float)NA);
    float sn, cs;
    sincosf(ang, &sn, &cs);
    const float s   = -RHO_F + ((float)det + 0.5f) * (2.0f * RHO_F / (float)ND);
    const float t0v = -RHO_F + 0.5f * DT_F;
    const float inv_dx = 1.0f / DX_F;

    const float e0 = -s * sn;
    const float e1 =  s * cs;
    // Padded-coordinate position: +1.5 = -0.5 (center) + 2 (ring offset).
    const float c0  = (e0 + t0v * cs + 20.0f) * inv_dx + 1.5f;
    const float c1  = (e1 + t0v * sn + 20.0f) * inv_dx + 1.5f;
    const float st0 = DT_F * cs * inv_dx;
    const float st1 = DT_F * sn * inv_dx;

    // Clip to bilinear support square |p| <= 20 + DX/2 (+ margin).
    const float LIM = 20.157f;
    const float inv_cs = 1.0f / cs;
    const float inv_sn = 1.0f / sn;
    float ta = (-LIM - e0) * inv_cs, tb = (LIM - e0) * inv_cs;
    float tc = (-LIM - e1) * inv_sn, td = (LIM - e1) * inv_sn;
    float tlo = fmaxf(fminf(ta, tb), fminf(tc, td));
    float thi = fminf(fmaxf(ta, tb), fmaxf(tc, td));

    const float inv_dt = 1.0f / DT_F;
    float fk0 = fmaxf(ceilf((tlo - t0v) * inv_dt), 0.0f);
    float fk1 = fminf(floorf((thi - t0v) * inv_dt), (float)(NT - 1));
    int kmin = (int)fk0;   // saturating cvt handles degenerate rays
    int kmax = (int)fk1;

    // Wave envelope: uniform loop bounds (lanes = consecutive detectors,
    // so the envelope is tight). Out-of-own-chord samples read zeros.
    int kminW = kmin, kmaxW = kmax;
    #pragma unroll
    for (int off = 32; off >= 1; off >>= 1) {
        kminW = min(kminW, __shfl_xor(kminW, off, 64));
        kmaxW = max(kmaxW, __shfl_xor(kmaxW, off, 64));
    }

    float acc = 0.0f;
    float fk  = (float)kminW;
    #pragma unroll 2
    for (int k = kminW; k <= kmaxW; ++k) {
        float i0 = fmaf(fk, st0, c0);
        float i1 = fmaf(fk, st1, c1);
        fk += 1.0f;
        // Clamp into [0.5, 131.49]: identity for in-chord samples
        // ([0.997,130.004]); anything else lands in the zero ring.
        i0 = fminf(fmaxf(i0, 0.5f), 131.49f);
        i1 = fminf(fmaxf(i1, 0.5f), 131.49f);
        float f0 = floorf(i0);
        float f1 = floorf(i1);
        float a0 = i0 - f0;
        float a1 = i1 - f1;
        int idx = (int)fmaf(f0, (float)PITCH, f1);   // exact (< 2^24)
        unsigned int u0 = P[idx];
        unsigned int u1 = P[idx + 1];
        half2v w = __builtin_amdgcn_cvt_pkrtz(1.0f - a0, a0);
        float left  = __builtin_amdgcn_fdot2(__builtin_bit_cast(half2v, u0), w, 0.0f, false);
        float right = __builtin_amdgcn_fdot2(__builtin_bit_cast(half2v, u1), w, 0.0f, false);
        acc += fmaf(a1, right - left, left);
    }

    if (valid) out[img * RAYS + lray] = acc * (DT_F / 12.0f);
}

extern "C" void kernel_launch(void* const* d_in, const int* in_sizes, int n_in,
                              void* d_out, int out_size, void* d_ws, size_t ws_size,
                              hipStream_t stream) {
    const float* x = (const float*)d_in[0];
    float* out = (float*)d_out;
    const int B = in_sizes[0] / (NI * NI);   // 8
    dim3 grid(B * 64);
    radon_fwd<<<grid, TPB, 0, stream>>>(x, out);
}

// Round 5
// 134.858 us; speedup vs baseline: 1.6405x; 1.0213x over previous
//
#include <hip/hip_runtime.h>
#include <stdint.h>

#define NI 128
#define NA 285
#define ND 183
#define NT 384
#define RAYS (NA * ND)        // 52155
#define PITCH 133             // dwords per packed row
#define PROWS 132
#define PLDS (PROWS * PITCH)  // 70,224 B -> 2 blocks/CU
#define NPAIR 92              // mirror det-pairs per angle: (j, 182-j), j=0..91
#define QTOT (NA * NPAIR)     // 26220 pair-slots per image
#define TPB 448               // 7 waves; 64 blocks/image -> 512 blocks = 2/CU
#define IDXMAX 17420          // 130*133 + 130: idx_mirror = IDXMAX - idx

typedef __fp16 half2v __attribute__((ext_vector_type(2)));

constexpr float PI_F  = 3.14159265358979323846f;
constexpr float RHO_F = 28.284271247461902f;   // 20*sqrt(2)
constexpr float DX_F  = 0.3125f;
constexpr float DT_F  = 2.0f * RHO_F / NT;

// Mirror-paired Radon: each lane integrates ray (a, j) AND its mirror
// (a, 182-j) simultaneously. s' = -s => sample coords i' = 131 - i, so the
// mirror bilinear sample reuses f0,f1,a0,a1: idx' = 17420 - idx, weights
// swap (v_alignbit), horizontal blend uses 1-a1. Identical chord lengths =>
// zero divergence within a pair. Per-lane divergent k-loop (max-len per
// wave, no envelope union, no clamps).
__global__ __launch_bounds__(TPB) void radon_fwd(const float* __restrict__ x,
                                                 float* __restrict__ out) {
    __shared__ __align__(16) unsigned int P[PLDS];
    const int tid   = threadIdx.x;
    const int img   = blockIdx.x >> 6;
    const int chunk = blockIdx.x & 63;

    // Zero-fill (ring + spare); interior overwritten below.
    uint4* P4 = (uint4*)P;
    for (int i = tid; i < PLDS / 4; i += TPB) P4[i] = make_uint4(0, 0, 0, 0);
    __syncthreads();

    // Vertical-pair pack: P[pr*133+pc] = half2(pad[pr][pc], pad[pr+1][pc]),
    // pad = image with 2-cell zero ring (pad row/col = image index + 2).
    const float4* src = (const float4*)(x + img * NI * NI);
    for (int i = tid; i < 129 * 32; i += TPB) {
        int pr  = 1 + (i >> 5);
        int g   = i & 31;
        int rlo = pr - 2;              // -1..127
        int rhi = pr - 1;              //  0..128
        float4 vlo = (rlo >= 0)   ? src[rlo * 32 + g] : make_float4(0, 0, 0, 0);
        float4 vhi = (rhi <= 127) ? src[rhi * 32 + g] : make_float4(0, 0, 0, 0);
        int base = pr * PITCH + 2 + g * 4;
        P[base + 0] = __builtin_bit_cast(unsigned int, __builtin_amdgcn_cvt_pkrtz(vlo.x, vhi.x));
        P[base + 1] = __builtin_bit_cast(unsigned int, __builtin_amdgcn_cvt_pkrtz(vlo.y, vhi.y));
        P[base + 2] = __builtin_bit_cast(unsigned int, __builtin_amdgcn_cvt_pkrtz(vlo.z, vhi.z));
        P[base + 3] = __builtin_bit_cast(unsigned int, __builtin_amdgcn_cvt_pkrtz(vlo.w, vhi.w));
    }
    __syncthreads();

    const int  q     = chunk * TPB + tid;     // pair-slot within image
    const bool valid = q < QTOT;
    const int a = q / NPAIR;                  // magic-multiply
    const int j = q - a * NPAIR;              // det of left ray; right = 182-j

    const float ang = ((float)a + 0.5f) * (PI_F / (float)NA);
    float sn, cs;
    sincosf(ang, &sn, &cs);
    const float s   = -RHO_F + ((float)j + 0.5f) * (2.0f * RHO_F / (float)ND);
    const float t0v = -RHO_F + 0.5f * DT_F;
    const float inv_dx = 1.0f / DX_F;

    const float e0 = -s * sn;
    const float e1 =  s * cs;
    // Padded index coords: +1.5 = -0.5 (pixel center) + 2 (ring offset).
    const float c0  = (e0 + t0v * cs + 20.0f) * inv_dx + 1.5f;
    const float c1  = (e1 + t0v * sn + 20.0f) * inv_dx + 1.5f;
    const float st0 = DT_F * cs * inv_dx;
    const float st1 = DT_F * sn * inv_dx;

    // Per-lane clip to bilinear support |p| <= 20 + DX/2 (+ fp margin).
    const float LIM = 20.157f;
    const float inv_cs = 1.0f / cs;
    const float inv_sn = 1.0f / sn;
    float ta = (-LIM - e0) * inv_cs, tb = (LIM - e0) * inv_cs;
    float tc = (-LIM - e1) * inv_sn, td = (LIM - e1) * inv_sn;
    float tlo = fmaxf(fminf(ta, tb), fminf(tc, td));
    float thi = fminf(fmaxf(ta, tb), fmaxf(tc, td));

    const float inv_dt = 1.0f / DT_F;
    float fk0 = fmaxf(ceilf((tlo - t0v) * inv_dt), 0.0f);
    float fk1 = fminf(floorf((thi - t0v) * inv_dt), (float)(NT - 1));
    int kmin = (int)fk0;   // saturating cvt handles degenerate rays
    int kmax = (int)fk1;
    if (!valid) { kmin = 0; kmax = -1; }

    float i0 = fmaf(fk0, st0, c0);
    float i1 = fmaf(fk0, st1, c1);
    float accL = 0.0f, accR = 0.0f;

    // Divergent per-lane loop: wave runs max(len) passes; lanes advance
    // their own k concurrently. Keep body tight; no unroll (exec churn).
    #pragma unroll 1
    for (int k = kmin; k <= kmax; ++k) {
        float f0 = floorf(i0);
        float f1 = floorf(i1);
        float a0 = i0 - f0;
        float a1 = i1 - f1;
        int idx = (int)fmaf(f0, (float)PITCH, f1);   // exact (< 2^24)
        i0 += st0;
        i1 += st1;
        unsigned int u0 = P[idx];
        unsigned int u1 = P[idx + 1];
        unsigned int m0 = P[IDXMAX - idx];           // mirror: rows/cols flip
        unsigned int m1 = P[IDXMAX - idx + 1];
        unsigned int wb = __builtin_bit_cast(unsigned int,
                              __builtin_amdgcn_cvt_pkrtz(1.0f - a0, a0));
        unsigned int wbm = __builtin_amdgcn_alignbit(wb, wb, 16); // swap halves
        half2v w  = __builtin_bit_cast(half2v, wb);
        half2v wm = __builtin_bit_cast(half2v, wbm);
        float lL = __builtin_amdgcn_fdot2(__builtin_bit_cast(half2v, u0), w, 0.0f, false);
        float rL = __builtin_amdgcn_fdot2(__builtin_bit_cast(half2v, u1), w, 0.0f, false);
        float lR = __builtin_amdgcn_fdot2(__builtin_bit_cast(half2v, m0), wm, 0.0f, false);
        float rR = __builtin_amdgcn_fdot2(__builtin_bit_cast(half2v, m1), wm, 0.0f, false);
        accL += fmaf(a1, rL - lL, lL);
        accR += fmaf(1.0f - a1, rR - lR, lR);
    }

    if (valid) {
        const float sc = DT_F / 12.0f;
        const int base = img * RAYS + a * ND;
        out[base + j]        = accL * sc;
        out[base + (182 - j)] = accR * sc;   // j==91 writes same value twice
    }
}

extern "C" void kernel_launch(void* const* d_in, const int* in_sizes, int n_in,
                              void* d_out, int out_size, void* d_ws, size_t ws_size,
                              hipStream_t stream) {
    const float* x = (const float*)d_in[0];
    float* out = (float*)d_out;
    const int B = in_sizes[0] / (NI * NI);   // 8
    dim3 grid(B * 64);
    radon_fwd<<<grid, TPB, 0, stream>>>(x, out);
}

// Round 6
// 113.143 us; speedup vs baseline: 1.9553x; 1.1919x over previous
//
#include <hip/hip_runtime.h>
#include <stdint.h>

#define NI 128
#define NA 285
#define ND 183
#define NT 384
#define RAYS (NA * ND)        // 52155
#define PITCH 133             // dwords per packed row
#define PROWS 132
#define PLDS (PROWS * PITCH)  // 70,224 B -> 2 blocks/CU
#define NPAIR 92              // mirror det-pairs per angle: (j, 182-j)
#define UNITS_PER_J (NA * 2)  // 570: (angle, half) units at fixed j
#define UTOT (NPAIR * UNITS_PER_J)   // 52,440 units per image
#define TPB 832               // 13 waves; 64 blocks/img -> 512 blocks = 2/CU
#define UPB 820               // units per block (even: keeps h-pairs adjacent)
#define IDXMAX 17420          // 130*133+130: idx_mirror = IDXMAX - idx

typedef __fp16 half2v __attribute__((ext_vector_type(2)));

constexpr float PI_F  = 3.14159265358979323846f;
constexpr float RHO_F = 28.284271247461902f;   // 20*sqrt(2)
constexpr float DX_F  = 0.3125f;
constexpr float DT_F  = 2.0f * RHO_F / NT;

// Mirror-paired + chord-split Radon. Each lane: mirror-pair (a,j)/(a,182-j),
// HALF the chord (h=0 walks down from the chord middle, h=1 walks up).
// Walking outward means over-run samples exit the support square -> the
// [0.5,130.49] clamp lands them in the 2-cell zero ring -> contribute 0
// exactly (no double counting across halves, no divergence). Wave =
// 32 adjacent angles at fixed j (tight half-chord envelope); uniform loop.
__global__ __launch_bounds__(TPB) void radon_fwd(const float* __restrict__ x,
                                                 float* __restrict__ out) {
    __shared__ __align__(16) unsigned int P[PLDS];
    const int tid   = threadIdx.x;
    const int img   = blockIdx.x >> 6;
    const int chunk = blockIdx.x & 63;

    // Zero-fill (ring + spare); interior overwritten below.
    uint4* P4 = (uint4*)P;
    for (int i = tid; i < PLDS / 4; i += TPB) P4[i] = make_uint4(0, 0, 0, 0);
    __syncthreads();

    // Vertical-pair pack: P[pr*133+pc] = half2(pad[pr][pc], pad[pr+1][pc]),
    // pad = image with 2-cell zero ring (pad row/col = image index + 2).
    const float4* src = (const float4*)(x + img * NI * NI);
    for (int i = tid; i < 129 * 32; i += TPB) {
        int pr  = 1 + (i >> 5);
        int g   = i & 31;
        int rlo = pr - 2;              // -1..127
        int rhi = pr - 1;              //  0..128
        float4 vlo = (rlo >= 0)   ? src[rlo * 32 + g] : make_float4(0, 0, 0, 0);
        float4 vhi = (rhi <= 127) ? src[rhi * 32 + g] : make_float4(0, 0, 0, 0);
        int base = pr * PITCH + 2 + g * 4;
        P[base + 0] = __builtin_bit_cast(unsigned int, __builtin_amdgcn_cvt_pkrtz(vlo.x, vhi.x));
        P[base + 1] = __builtin_bit_cast(unsigned int, __builtin_amdgcn_cvt_pkrtz(vlo.y, vhi.y));
        P[base + 2] = __builtin_bit_cast(unsigned int, __builtin_amdgcn_cvt_pkrtz(vlo.z, vhi.z));
        P[base + 3] = __builtin_bit_cast(unsigned int, __builtin_amdgcn_cvt_pkrtz(vlo.w, vhi.w));
    }
    __syncthreads();

    const int  u     = chunk * UPB + tid;
    const bool valid = (tid < UPB) && (u < UTOT);
    const int j = u / UNITS_PER_J;            // magic-multiply
    const int r = u - j * UNITS_PER_J;
    const int a = r >> 1;                     // angle
    const int h = r & 1;                      // chord half (0=down, 1=up)

    const float ang = ((float)a + 0.5f) * (PI_F / (float)NA);
    float sn, cs;
    sincosf(ang, &sn, &cs);
    const float s   = -RHO_F + ((float)j + 0.5f) * (2.0f * RHO_F / (float)ND);
    const float t0v = -RHO_F + 0.5f * DT_F;
    const float inv_dx = 1.0f / DX_F;

    const float e0 = -s * sn;
    const float e1 =  s * cs;
    // Padded index coords: +1.5 = -0.5 (pixel center) + 2 (ring offset).
    const float c0  = (e0 + t0v * cs + 20.0f) * inv_dx + 1.5f;
    const float c1  = (e1 + t0v * sn + 20.0f) * inv_dx + 1.5f;
    const float st0 = DT_F * cs * inv_dx;
    const float st1 = DT_F * sn * inv_dx;

    // Clip to bilinear support |p| <= 20 + DX/2 (+ fp margin).
    const float LIM = 20.157f;
    const float inv_cs = 1.0f / cs;
    const float inv_sn = 1.0f / sn;
    float ta = (-LIM - e0) * inv_cs, tb = (LIM - e0) * inv_cs;
    float tc = (-LIM - e1) * inv_sn, td = (LIM - e1) * inv_sn;
    float tlo = fmaxf(fminf(ta, tb), fminf(tc, td));
    float thi = fminf(fmaxf(ta, tb), fmaxf(tc, td));

    const float inv_dt = 1.0f / DT_F;
    float fk0 = fminf(fmaxf(ceilf((tlo - t0v) * inv_dt), 0.0f), 384.0f);
    float fk1 = fminf(fmaxf(floorf((thi - t0v) * inv_dt), -1.0f), 383.0f);
    const int kmin = (int)fk0;
    const int kmax = (int)fk1;
    const int kmid = (kmin + kmax + 1) >> 1;

    int mylen = h ? (kmax - kmid + 1) : (kmid - kmin);
    if (mylen < 0 || !valid) mylen = 0;

    // Wave envelope (lanes = adjacent angles at fixed j -> tight).
    int Lw = mylen;
    #pragma unroll
    for (int off = 32; off >= 1; off >>= 1)
        Lw = max(Lw, __shfl_xor(Lw, off, 64));

    const float sgn  = h ? 1.0f : -1.0f;
    const float st0h = st0 * sgn;
    const float st1h = st1 * sgn;
    const float ks   = (float)(h ? kmid : kmid - 1);
    float i0 = fmaf(ks, st0, c0);
    float i1 = fmaf(ks, st1, c1);
    float accL = 0.0f, accR = 0.0f;

    #pragma unroll 2
    for (int m = 0; m < Lw; ++m) {
        // Clamp [0.5, 130.49]: identity for in-chord samples ([0.998,130.003]);
        // out-of-own-half samples land in the zero ring (mirror idx stays
        // in [0, 17421] by construction).
        float q0 = fminf(fmaxf(i0, 0.5f), 130.49f);
        float q1 = fminf(fmaxf(i1, 0.5f), 130.49f);
        i0 += st0h;
        i1 += st1h;
        float f0 = floorf(q0);
        float f1 = floorf(q1);
        float a0 = q0 - f0;
        float a1 = q1 - f1;
        int idx = (int)fmaf(f0, (float)PITCH, f1);   // exact (< 2^24)
        unsigned int u0 = P[idx];
        unsigned int u1 = P[idx + 1];
        unsigned int m0 = P[IDXMAX - idx];           // mirror ray, flipped
        unsigned int m1 = P[IDXMAX - idx + 1];
        unsigned int wb = __builtin_bit_cast(unsigned int,
                              __builtin_amdgcn_cvt_pkrtz(1.0f - a0, a0));
        unsigned int wbm = __builtin_amdgcn_alignbit(wb, wb, 16); // swap halves
        half2v w  = __builtin_bit_cast(half2v, wb);
        half2v wm = __builtin_bit_cast(half2v, wbm);
        float lL = __builtin_amdgcn_fdot2(__builtin_bit_cast(half2v, u0), w, 0.0f, false);
        float rL = __builtin_amdgcn_fdot2(__builtin_bit_cast(half2v, u1), w, 0.0f, false);
        float lR = __builtin_amdgcn_fdot2(__builtin_bit_cast(half2v, m0), wm, 0.0f, false);
        float rR = __builtin_amdgcn_fdot2(__builtin_bit_cast(half2v, m1), wm, 0.0f, false);
        accL += fmaf(a1, rL - lL, lL);
        accR += fmaf(1.0f - a1, rR - lR, lR);
    }

    // Combine the two chord halves (adjacent lanes).
    accL += __shfl_xor(accL, 1, 64);
    accR += __shfl_xor(accR, 1, 64);

    if (valid) {
        const float sc = DT_F / 12.0f;
        const int base = img * RAYS + a * ND;
        // h=0 lane writes detector j, h=1 lane writes mirror 182-j.
        // (j==91 double-writes the same value — benign.)
        int det = h ? (182 - j) : j;
        float v = h ? accR : accL;
        out[base + det] = v * sc;
    }
}

extern "C" void kernel_launch(void* const* d_in, const int* in_sizes, int n_in,
                              void* d_out, int out_size, void* d_ws, size_t ws_size,
                              hipStream_t stream) {
    const float* x = (const float*)d_in[0];
    float* out = (float*)d_out;
    const int B = in_sizes[0] / (NI * NI);   // 8
    dim3 grid(B * 64);
    radon_fwd<<<grid, TPB, 0, stream>>>(x, out);
}